// Round 6
// baseline (13.531 us; speedup 1.0000x reference)
//
#include <hip/hip_runtime.h>
#include <math.h>

// features: (B=8, C=64, L=8192) fp32; H=32, UNIT=512, W=544
// out[b,h,l] = corr(col l, col l+1+h) within block n=l/512
#define CC    64
#define LL    8192
#define HH    32
#define UNITL 512
#define TC    128          // output columns per workgroup (quarter window)
#define WC    160          // TC + 32 halo; 10 row-blocks of 16
#define XSTR  72           // Xt row stride in shorts (64 padded to 72: 144B row
                           //  -> quad = (9*row + slot16B) & 7, bank-uniform)
#define BSTR  132          // band row stride (floats)
#define EPSF  1e-12f

typedef __attribute__((ext_vector_type(8))) short bf16x8;
typedef __attribute__((ext_vector_type(4))) float f32x4;
typedef __attribute__((ext_vector_type(4))) unsigned int u32x4;

// LDS plan (66,560 B -> 2 blocks/CU):
//   u.xs   : packed (hi<<16|lo) window chunk [32 c][160 w]  20,480 B
//   u.s    : band[32][132] + ms[160] + ns[160]              18,176 B (reuses xs)
//   xhi/xlo: transposed bf16 [160 w][72 c-padded]         2x23,040 B
union U {
    unsigned int xs[32][WC];
    struct {
        float band[HH][BSTR];
        float ms[WC];
        float ns[WC];
    } s;
};

__device__ __forceinline__ unsigned rne_bf16(unsigned ub) {
    return (ub + 0x7FFFu + ((ub >> 16) & 1u)) >> 16;   // RNE f32->bf16 (finite)
}
__device__ __forceinline__ float bf16_to_f(unsigned short h) {
    return __uint_as_float(((unsigned)h) << 16);
}

__global__ __launch_bounds__(512, 4)
void tsm_kernel(const float* __restrict__ feat, float* __restrict__ out) {
    __shared__ U u;
    __shared__ short xhi[WC * XSTR];
    __shared__ short xlo[WC * XSTR];

    const int tid  = threadIdx.x;
    const int lane = tid & 63;
    const int wv   = tid >> 6;            // 0..7
    const int blk  = blockIdx.x;          // 0..511
    const int q4   = blk & 3;
    const int n    = (blk >> 2) & 15;
    const int b    = blk >> 6;
    const int col0 = n * UNITL + q4 * TC;

    const float* fb = feat + (size_t)b * CC * LL;

    // ---- stage + hi/lo-pack + transpose, two 32-channel chunks ----
    for (int chunk = 0; chunk < 2; ++chunk) {
        // (a) coalesced f32x4 load -> pack (hi|lo) u32x4 -> row-major LDS
        #pragma unroll
        for (int it = 0; it < 3; ++it) {
            int tau = it * 512 + tid;                  // 0..1279 (32 c x 40 q)
            if (tau < 32 * (WC / 4)) {
                int c  = tau / (WC / 4);
                int qq = tau - c * (WC / 4);
                int l  = col0 + 4 * qq;
                f32x4 v = {0.f, 0.f, 0.f, 0.f};
                if (l < LL)
                    v = *reinterpret_cast<const f32x4*>(fb + (size_t)(chunk * 32 + c) * LL + l);
                u32x4 pk;
                #pragma unroll
                for (int e = 0; e < 4; ++e) {
                    unsigned ub = __float_as_uint(v[e]);
                    unsigned hr = rne_bf16(ub);
                    float lo = v[e] - __uint_as_float(hr << 16);   // exact
                    unsigned lr = rne_bf16(__float_as_uint(lo));
                    pk[e] = (hr << 16) | (lr & 0xFFFFu);
                }
                *reinterpret_cast<u32x4*>(&u.xs[c][4 * qq]) = pk;
            }
        }
        __syncthreads();
        // (b) transpose-unpack: task (c8,w) -> Xt[w][chunk*32+8c8 .. +8)
        #pragma unroll
        for (int it = 0; it < 2; ++it) {
            int tau = it * 512 + tid;                  // 0..639 (4 c8 x 160 w)
            if (tau < 4 * WC) {
                int c8 = tau / WC;
                int w  = tau - c8 * WC;
                bf16x8 Hv, Lv;
                #pragma unroll
                for (int j = 0; j < 8; ++j) {
                    unsigned p = u.xs[c8 * 8 + j][w];
                    Hv[j] = (short)(p >> 16);
                    Lv[j] = (short)(p & 0xFFFFu);
                }
                int base = w * XSTR + chunk * 32 + c8 * 8;
                *reinterpret_cast<bf16x8*>(&xhi[base]) = Hv;
                *reinterpret_cast<bf16x8*>(&xlo[base]) = Lv;
            }
        }
        __syncthreads();   // also protects xs reuse (chunk 2 / union)
    }

    // ---- fused phase: column stats + banded Gram via MFMA ----
    // stats (threads 0..159): read Xt row w; xs is dead -> write u.s.ms/ns
    if (tid < WC) {
        float s = 0.f, ss = 0.f;
        #pragma unroll
        for (int k = 0; k < 8; ++k) {
            bf16x8 Hv = *reinterpret_cast<const bf16x8*>(&xhi[tid * XSTR + 8 * k]);
            bf16x8 Lv = *reinterpret_cast<const bf16x8*>(&xlo[tid * XSTR + 8 * k]);
            #pragma unroll
            for (int j = 0; j < 8; ++j) {
                float x = bf16_to_f((unsigned short)Hv[j]) + bf16_to_f((unsigned short)Lv[j]);
                s += x; ss += x * x;
            }
        }
        float m = s * (1.0f / CC);
        u.s.ms[tid] = m;
        u.s.ns[tid] = sqrtf(fmaxf(ss - (float)CC * m * m, 0.f));
    }
    // MFMA: wave wv owns output row-block wv; tiles (wv, wv+dj), dj=0..2
    {
        const int r16 = lane & 15;
        const int g   = lane >> 4;
        bf16x8 fh[3][2], fl[3][2];
        #pragma unroll
        for (int bb = 0; bb < 3; ++bb) {
            int row  = 16 * (wv + bb) + r16;           // <= 159
            int base = row * XSTR;
            #pragma unroll
            for (int kk = 0; kk < 2; ++kk) {
                int off = base + (g + 4 * kk) * 8;
                fh[bb][kk] = *reinterpret_cast<const bf16x8*>(&xhi[off]);
                fl[bb][kk] = *reinterpret_cast<const bf16x8*>(&xlo[off]);
            }
        }
        #pragma unroll
        for (int dj = 0; dj < 3; ++dj) {
            f32x4 acc = {0.f, 0.f, 0.f, 0.f};
            acc = __builtin_amdgcn_mfma_f32_16x16x32_bf16(fh[0][0], fh[dj][0], acc, 0, 0, 0);
            acc = __builtin_amdgcn_mfma_f32_16x16x32_bf16(fh[0][1], fh[dj][1], acc, 0, 0, 0);
            acc = __builtin_amdgcn_mfma_f32_16x16x32_bf16(fh[0][0], fl[dj][0], acc, 0, 0, 0);
            acc = __builtin_amdgcn_mfma_f32_16x16x32_bf16(fh[0][1], fl[dj][1], acc, 0, 0, 0);
            acc = __builtin_amdgcn_mfma_f32_16x16x32_bf16(fl[0][0], fh[dj][0], acc, 0, 0, 0);
            acc = __builtin_amdgcn_mfma_f32_16x16x32_bf16(fl[0][1], fh[dj][1], acc, 0, 0, 0);
            // C/D (m89-verified): col = lane&15 -> tp; row = 4*(lane>>4)+reg -> t
            #pragma unroll
            for (int r = 0; r < 4; ++r) {
                int t  = 16 * wv + 4 * g + r;          // 0..127
                int tp = 16 * (wv + dj) + r16;         // 0..159
                int h  = tp - t - 1;
                if ((unsigned)h < 32u) u.s.band[h][t] = acc[r];
            }
        }
    }
    __syncthreads();

    // ---- epilogue: normalize + mask + coalesced f32x4 store ----
    {
        const int h  = tid >> 4;                       // 0..31
        const int cb = tid & 15;
        float* ob = out + ((size_t)b * HH + h) * LL + col0;
        #pragma unroll
        for (int k = 0; k < 2; ++k) {
            int t0 = 4 * (cb + 16 * k);                // 0..124
            f32x4 v = *reinterpret_cast<const f32x4*>(&u.s.band[h][t0]);
            f32x4 res;
            #pragma unroll
            for (int e = 0; e < 4; ++e) {
                int t  = t0 + e;
                int tp = t + 1 + h;
                float num  = v[e] - (float)CC * u.s.ms[t] * u.s.ms[tp];
                float den  = fmaxf(u.s.ns[t] * u.s.ns[tp], EPSF);
                float corr = num * __builtin_amdgcn_rcpf(den);
                if (col0 + tp >= LL) corr = 0.f;       // reference band mask
                res[e] = corr;
            }
            *reinterpret_cast<f32x4*>(ob + t0) = res;
        }
    }
}

extern "C" void kernel_launch(void* const* d_in, const int* in_sizes, int n_in,
                              void* d_out, int out_size, void* d_ws, size_t ws_size,
                              hipStream_t stream) {
    const float* feat = (const float*)d_in[0];
    float* out = (float*)d_out;
    // 512 blocks = B(8) x n(16) x quarters(4); 512 threads; 2 blocks/CU.
    tsm_kernel<<<dim3(512), dim3(512), 0, stream>>>(feat, out);
}